// Round 6
// baseline (417.425 us; speedup 1.0000x reference)
//
#include <hip/hip_runtime.h>

#define N_COARSE_C 250000
#define KNB 9
#define CIN 64
#define COUT 64
#define NKK 18   // K = 576 = 18 * 32

typedef __attribute__((ext_vector_type(8))) short short8;
typedef __attribute__((ext_vector_type(4))) float f32x4;

__device__ __forceinline__ unsigned short f2bf(float x) {
    __bf16 h = (__bf16)x;                       // fptrunc = RNE; pairs fuse to v_cvt_pk_bf16_f32
    return __builtin_bit_cast(unsigned short, h);
}

// 512 threads = 8 waves; wave w owns coarse rows [c0, c0+16).
// MFMA 16x16x32 bf16, fp32 accum. A-fragment (row=lane&15, k=(lane>>4)*8+e) is
// gathered from lv as f32 (2x dwordx4 per lane per K-step), relu'd + cvt'd to
// bf16 in-register. W staged once per block into LDS pre-arranged in B-fragment
// order so hot-loop B loads are contiguous, conflict-free ds_read_b128.
__global__ __launch_bounds__(512, 4) void relu_coarsen_mfma(
    const float* __restrict__ lv,      // [1e6][64] f32
    const int*   __restrict__ nbr,     // [250000][9] int32
    const float* __restrict__ W,       // [576][64] f32
    const float* __restrict__ bias,    // [64] f32
    float*       __restrict__ out)     // [250000][64] f32
{
    __shared__ short wf[NKK * 4 * 64 * 8];  // 36864 bf16 = 73728 B -> 2 blocks/CU

    const int tid = threadIdx.x;

    // Stage W[k][n] (f32) -> bf16 LDS in B-fragment order:
    // wf[((kk*4 + (n>>4))*64 + gq*16 + (n&15))*8 + (k&7)], kk=k>>5, gq=(k>>3)&3.
    // Pack (k, k+1) for same n into one ds_write_b32 (e even -> aligned dword).
    for (int p = tid; p < (576 * 64) / 2; p += 512) {
        const int n  = p & 63;
        const int k  = (p >> 6) * 2;
        const float a0 = W[k * 64 + n];          // wave reads 256B contiguous
        const float a1 = W[(k + 1) * 64 + n];
        const unsigned pk = (unsigned)f2bf(a0) | ((unsigned)f2bf(a1) << 16);
        const int kk = k >> 5;
        const int gq = (k >> 3) & 3;
        const int e  = k & 7;
        const int sidx = ((kk * 4 + (n >> 4)) * 64 + gq * 16 + (n & 15)) * 8 + e;
        *reinterpret_cast<unsigned*>(&wf[sidx]) = pk;
    }
    __syncthreads();

    const int lane = tid & 63;
    const int wave = tid >> 6;
    const int m    = lane & 15;   // A row within wave tile / D col
    const int g    = lane >> 4;   // k-group

    const int c0 = blockIdx.x * 128 + wave * 16;  // wave's first coarse row
    int c = c0 + m;
    if (c >= N_COARSE_C) c = N_COARSE_C - 1;      // clamp (stores masked below)

    int nb[KNB];
    #pragma unroll
    for (int j = 0; j < KNB; ++j) nb[j] = nbr[c * KNB + j];

    f32x4 acc[4];
    #pragma unroll
    for (int nt = 0; nt < 4; ++nt) acc[nt] = (f32x4){0.f, 0.f, 0.f, 0.f};

    #pragma unroll
    for (int kk = 0; kk < NKK; ++kk) {
        const int j  = kk >> 1;                       // static after unroll
        const int cb = ((kk & 1) << 5) + g * 8;       // lane's channel base
        const int row = nb[j];
        short8 a;
        if (row >= 0) {
            const f32x4* src = reinterpret_cast<const f32x4*>(
                lv + (size_t)row * CIN + cb);
            f32x4 v0 = src[0];
            f32x4 v1 = src[1];
            #pragma unroll
            for (int e = 0; e < 4; ++e) {
                a[e]     = (short)f2bf(fmaxf(v0[e], 0.f));
                a[e + 4] = (short)f2bf(fmaxf(v1[e], 0.f));
            }
        } else {
            #pragma unroll
            for (int e = 0; e < 8; ++e) a[e] = (short)0;
        }
        #pragma unroll
        for (int nt = 0; nt < 4; ++nt) {
            const short8 bf = *reinterpret_cast<const short8*>(
                &wf[((kk * 4 + nt) * 64 + lane) * 8]);  // conflict-free b128
            acc[nt] = __builtin_amdgcn_mfma_f32_16x16x32_bf16(a, bf, acc[nt], 0, 0, 0);
        }
    }

    // Epilogue: D col = lane&15 (=m), D row = g*4 + r. Add bias, store f32.
    #pragma unroll
    for (int r = 0; r < 4; ++r) {
        const int cr = c0 + g * 4 + r;
        if (cr < N_COARSE_C) {
            #pragma unroll
            for (int nt = 0; nt < 4; ++nt) {
                const int n = nt * 16 + m;
                out[(size_t)cr * COUT + n] = acc[nt][r] + bias[n];
            }
        }
    }
}

extern "C" void kernel_launch(void* const* d_in, const int* in_sizes, int n_in,
                              void* d_out, int out_size, void* d_ws, size_t ws_size,
                              hipStream_t stream) {
    const float* lv   = (const float*)d_in[0];
    const int*   nbr  = (const int*)d_in[1];
    const float* W    = (const float*)d_in[2];
    const float* b    = (const float*)d_in[3];
    float* out = (float*)d_out;
    const int grid = (N_COARSE_C + 127) / 128;  // 1954 blocks
    relu_coarsen_mfma<<<grid, 512, 0, stream>>>(lv, nbr, W, b, out);
}